// Round 7
// baseline (472.840 us; speedup 1.0000x reference)
//
#include <hip/hip_runtime.h>

#define S_LEN 2048
#define D_MODEL 1024
#define NHEAD 16
#define DHEAD 64

typedef __attribute__((ext_vector_type(8))) short bf16x8;
typedef __attribute__((ext_vector_type(4))) float f32x4;

__device__ __forceinline__ unsigned short bf16_rne(float x) {
    unsigned int u = __float_as_uint(x);
    u += 0x7FFFu + ((u >> 16) & 1u);
    return (unsigned short)(u >> 16);
}
__device__ __forceinline__ float bf16_f(unsigned short h) {
    return __uint_as_float(((unsigned int)h) << 16);
}

// ============ Merged GEMM: kqv = inputs @ W + b, split-bf16 outputs ============
// bx<16: K/Q columns [0,2048) row-major into khi/klo.
// bx>=16: V columns [2048,3072) stored TRANSPOSED (computes C^T via operand swap).
__global__ __launch_bounds__(256) void gemm_fused(
        const float* __restrict__ A, const float* __restrict__ Wm,
        const float* __restrict__ bias,
        unsigned short* __restrict__ khi, unsigned short* __restrict__ klo,
        unsigned short* __restrict__ vthi, unsigned short* __restrict__ vtlo) {
    __shared__ unsigned short Ash[128*36], Asl[128*36], Bth[128*36], Btl[128*36];
    const int tid = threadIdx.x;
    const int bx = blockIdx.x;
    const bool vpath = bx >= 16;
    const int n0 = vpath ? 2048 + (bx - 16) * 128 : bx * 128;
    const int m0 = blockIdx.y * 128;
    const int lane = tid & 63, wid = tid >> 6;
    const int wm = wid >> 1, wn = wid & 1;
    const int lr = lane & 15, lc = lane >> 4;
    const int ar = tid >> 1, akc = (tid & 1) * 16;
    const int bk2 = (tid & 15) * 2, bnc = (tid >> 4) * 8;

    f32x4 acc[4][4];
    #pragma unroll
    for (int i = 0; i < 4; ++i)
        #pragma unroll
        for (int j = 0; j < 4; ++j) acc[i][j] = (f32x4){0.f, 0.f, 0.f, 0.f};

    for (int k0 = 0; k0 < D_MODEL; k0 += 32) {
        const float* ap = A + (size_t)(m0 + ar) * D_MODEL + k0 + akc;
        float4 a0 = *(const float4*)(ap);
        float4 a1 = *(const float4*)(ap + 4);
        float4 a2 = *(const float4*)(ap + 8);
        float4 a3 = *(const float4*)(ap + 12);
        const float* wp0 = Wm + (size_t)(k0 + bk2) * 3072 + n0 + bnc;
        const float* wp1 = wp0 + 3072;
        float4 w00 = *(const float4*)(wp0), w01 = *(const float4*)(wp0 + 4);
        float4 w10 = *(const float4*)(wp1), w11 = *(const float4*)(wp1 + 4);
        __syncthreads();
        {
            float af[16] = {a0.x,a0.y,a0.z,a0.w, a1.x,a1.y,a1.z,a1.w,
                            a2.x,a2.y,a2.z,a2.w, a3.x,a3.y,a3.z,a3.w};
            unsigned short hs[16], ls[16];
            #pragma unroll
            for (int i = 0; i < 16; ++i) {
                hs[i] = bf16_rne(af[i]);
                ls[i] = bf16_rne(af[i] - bf16_f(hs[i]));
            }
            #pragma unroll
            for (int i = 0; i < 16; i += 4) {
                *(ushort4*)&Ash[ar*36 + akc + i] = make_ushort4(hs[i],hs[i+1],hs[i+2],hs[i+3]);
                *(ushort4*)&Asl[ar*36 + akc + i] = make_ushort4(ls[i],ls[i+1],ls[i+2],ls[i+3]);
            }
            float r0[8] = {w00.x,w00.y,w00.z,w00.w, w01.x,w01.y,w01.z,w01.w};
            float r1[8] = {w10.x,w10.y,w10.z,w10.w, w11.x,w11.y,w11.z,w11.w};
            #pragma unroll
            for (int i = 0; i < 8; ++i) {
                unsigned short h0 = bf16_rne(r0[i]), h1 = bf16_rne(r1[i]);
                unsigned short l0 = bf16_rne(r0[i] - bf16_f(h0));
                unsigned short l1 = bf16_rne(r1[i] - bf16_f(h1));
                *(ushort2*)&Bth[(bnc + i)*36 + bk2] = make_ushort2(h0, h1);
                *(ushort2*)&Btl[(bnc + i)*36 + bk2] = make_ushort2(l0, l1);
            }
        }
        __syncthreads();
        // X = row-side frags (wm), Y = col-side frags (wn); v-path swaps tiles.
        const unsigned short* Xh = vpath ? Bth : Ash;
        const unsigned short* Xl = vpath ? Btl : Asl;
        const unsigned short* Yh = vpath ? Ash : Bth;
        const unsigned short* Yl = vpath ? Asl : Btl;
        bf16x8 fXh[4], fXl[4], fYh[4], fYl[4];
        #pragma unroll
        for (int i = 0; i < 4; ++i) {
            int rx = (wm*64 + i*16 + lr)*36 + lc*8;
            int ry = (wn*64 + i*16 + lr)*36 + lc*8;
            fXh[i] = *(const bf16x8*)&Xh[rx];
            fXl[i] = *(const bf16x8*)&Xl[rx];
            fYh[i] = *(const bf16x8*)&Yh[ry];
            fYl[i] = *(const bf16x8*)&Yl[ry];
        }
        #pragma unroll
        for (int mi = 0; mi < 4; ++mi)
            #pragma unroll
            for (int ni = 0; ni < 4; ++ni) {
                acc[mi][ni] = __builtin_amdgcn_mfma_f32_16x16x32_bf16(fXh[mi], fYh[ni], acc[mi][ni], 0, 0, 0);
                acc[mi][ni] = __builtin_amdgcn_mfma_f32_16x16x32_bf16(fXh[mi], fYl[ni], acc[mi][ni], 0, 0, 0);
                acc[mi][ni] = __builtin_amdgcn_mfma_f32_16x16x32_bf16(fXl[mi], fYh[ni], acc[mi][ni], 0, 0, 0);
            }
    }
    if (!vpath) {
        #pragma unroll
        for (int ni = 0; ni < 4; ++ni) {
            int n = n0 + wn*64 + ni*16 + lr;
            float bv = bias[n];
            #pragma unroll
            for (int mi = 0; mi < 4; ++mi)
                #pragma unroll
                for (int r = 0; r < 4; ++r) {
                    int m = m0 + wm*64 + mi*16 + lc*4 + r;
                    float x = acc[mi][ni][r] + bv;
                    unsigned short hh = bf16_rne(x);
                    khi[(size_t)m*2048 + n] = hh;
                    klo[(size_t)m*2048 + n] = bf16_rne(x - bf16_f(hh));
                }
        }
    } else {
        #pragma unroll
        for (int mi = 0; mi < 4; ++mi)
            #pragma unroll
            for (int r = 0; r < 4; ++r) {
                int nr = n0 + wm*64 + mi*16 + lc*4 + r;   // global col in [2048,3072)
                float bv = bias[nr];
                int vrow = nr - 2048;
                #pragma unroll
                for (int ni = 0; ni < 4; ++ni) {
                    int sg = m0 + wn*64 + ni*16 + lr;
                    float x = acc[mi][ni][r] + bv;
                    unsigned short hh = bf16_rne(x);
                    vthi[(size_t)vrow*4096 + sg] = hh;
                    vtlo[(size_t)vrow*4096 + sg] = bf16_rne(x - bf16_f(hh));
                }
            }
    }
}

// ============ Fused attention, k-split across waves ============
// Block = 256 thr / 4 waves, q-tile 64. Each wave owns a 32-key slice of each
// 128-key tile -> per-wave loads are tiny; swapped QK^T (A=K,B=Q) makes the
// P fragment nearly lane-local (small per-wave LDS transpose, no barriers in loop).
// Epilogue reduces partial acc/den across waves via LDS.
#define NT 16   // 2048 / 128
__global__ __launch_bounds__(256, 2) void attn_mfma(
        const unsigned short* __restrict__ khi, const unsigned short* __restrict__ klo,
        const unsigned short* __restrict__ vthi, const unsigned short* __restrict__ vtlo,
        const float* __restrict__ masks, float* __restrict__ out) {
    __shared__ char pool[4*64*68*4];          // 69632 B: Wt (20480 B) then reused as accL
    __shared__ float denL[4][64];
    unsigned short* Wt = (unsigned short*)pool;   // per-wave region: wid*2560 ushorts, [q][k] stride 40
    float* accL = (float*)pool;                   // per-wave region: wid*64*68 floats

    const int tid = threadIdx.x;
    const int lane = tid & 63, wid = tid >> 6;
    const int lr = lane & 15, lc = lane >> 4;

    const int bid = blockIdx.x;
    const int work = (bid & 7) * 128 + (bid >> 3);   // XCD swizzle (1024 % 8 == 0, bijective)
    const int qb = work & 31;
    const int h  = (work >> 5) & 15;
    const int b  = work >> 9;
    const int q0 = qb * 64;
    const size_t srow = (size_t)b * S_LEN;

    // Q fragments (B-operand): q = q0+ni*16+lr, d = ks*32+lc*8, held all kernel
    bf16x8 qh[4][2], ql[4][2];
    #pragma unroll
    for (int ni = 0; ni < 4; ++ni)
        #pragma unroll
        for (int ks = 0; ks < 2; ++ks) {
            size_t off = (srow + q0 + ni*16 + lr) * 2048 + 1024 + h*64 + ks*32 + lc*8;
            qh[ni][ks] = *(const bf16x8*)(khi + off);
            ql[ni][ks] = *(const bf16x8*)(klo + off);
        }

    f32x4 acc[4][4];   // [ni: q-block][nd: d-block]
    #pragma unroll
    for (int i = 0; i < 4; ++i)
        #pragma unroll
        for (int j = 0; j < 4; ++j) acc[i][j] = (f32x4){0.f, 0.f, 0.f, 0.f};
    float den[4] = {0.f, 0.f, 0.f, 0.f};

    // K A-frags: rows = t*128 + wid*32 + mi*16 + lr, d = ks*32 + lc*8
    bf16x8 kh[2][2], kl[2][2];
    #pragma unroll
    for (int mi = 0; mi < 2; ++mi)
        #pragma unroll
        for (int ks = 0; ks < 2; ++ks) {
            size_t off = (srow + wid*32 + mi*16 + lr) * 2048 + h*64 + ks*32 + lc*8;
            kh[mi][ks] = *(const bf16x8*)(khi + off);
            kl[mi][ks] = *(const bf16x8*)(klo + off);
        }

    const int wtbase = wid * 2560;   // ushort index of this wave's Wt region

    for (int t = 0; t < NT; ++t) {
        // ---- QK^T (swapped: A=K slice, B=Q): u[mi][ni] reg r -> q=ni*16+lr, k=wid*32+mi*16+lc*4+r
        f32x4 u[2][4];
        #pragma unroll
        for (int mi = 0; mi < 2; ++mi)
            #pragma unroll
            for (int ni = 0; ni < 4; ++ni) u[mi][ni] = (f32x4){0.f, 0.f, 0.f, 0.f};
        #pragma unroll
        for (int ks = 0; ks < 2; ++ks)
            #pragma unroll
            for (int mi = 0; mi < 2; ++mi)
                #pragma unroll
                for (int ni = 0; ni < 4; ++ni) {
                    u[mi][ni] = __builtin_amdgcn_mfma_f32_16x16x32_bf16(kh[mi][ks], qh[ni][ks], u[mi][ni], 0, 0, 0);
                    u[mi][ni] = __builtin_amdgcn_mfma_f32_16x16x32_bf16(kh[mi][ks], ql[ni][ks], u[mi][ni], 0, 0, 0);
                    u[mi][ni] = __builtin_amdgcn_mfma_f32_16x16x32_bf16(kl[mi][ks], qh[ni][ks], u[mi][ni], 0, 0, 0);
                }
        // ---- prefetch next tile's K into the same frags (consumed next iteration)
        {
            int tn = (t + 1 < NT) ? t + 1 : t;
            #pragma unroll
            for (int mi = 0; mi < 2; ++mi)
                #pragma unroll
                for (int ks = 0; ks < 2; ++ks) {
                    size_t off = (srow + tn*128 + wid*32 + mi*16 + lr) * 2048 + h*64 + ks*32 + lc*8;
                    kh[mi][ks] = *(const bf16x8*)(khi + off);
                    kl[mi][ks] = *(const bf16x8*)(klo + off);
                }
        }
        // ---- V loads (issued early; consumed after exp)
        bf16x8 vh[4], vl[4];
        #pragma unroll
        for (int nd = 0; nd < 4; ++nd) {
            size_t voff = (size_t)(h*64 + nd*16 + lr) * 4096 + srow + t*128 + wid*32 + lc*8;
            vh[nd] = *(const bf16x8*)(vthi + voff);
            vl[nd] = *(const bf16x8*)(vtlo + voff);
        }
        // ---- masks for this lane's keys: k = t*128 + wid*32 + mi*16 + lc*4 + r
        float4 mk[2];
        #pragma unroll
        for (int mi = 0; mi < 2; ++mi)
            mk[mi] = *(const float4*)&masks[b*S_LEN + t*128 + wid*32 + mi*16 + lc*4];
        // ---- exp(elu-clip), pack to bf16 pairs, per-wave LDS transpose, den accum
        #pragma unroll
        for (int mi = 0; mi < 2; ++mi) {
            float mks[4] = {mk[mi].x, mk[mi].y, mk[mi].z, mk[mi].w};
            #pragma unroll
            for (int ni = 0; ni < 4; ++ni) {
                #pragma unroll
                for (int p = 0; p < 2; ++p) {
                    float x0 = u[mi][ni][2*p],   x1 = u[mi][ni][2*p+1];
                    float e0 = __expf(fminf(x0, 0.f)), e1 = __expf(fminf(x1, 0.f));
                    float t0 = x0 > 0.f ? x0 : e0 - 1.f;
                    float t1 = x1 > 0.f ? x1 : e1 - 1.f;
                    t0 = fminf(t0, 10.f); t1 = fminf(t1, 10.f);
                    float w0 = __expf(t0) * mks[2*p];
                    float w1 = __expf(t1) * mks[2*p+1];
                    unsigned short b0 = bf16_rne(w0), b1 = bf16_rne(w1);
                    den[ni] += bf16_f(b0) + bf16_f(b1);
                    unsigned int packed = (unsigned int)b0 | ((unsigned int)b1 << 16);
                    // Wt[q][k]: q = ni*16+lr (stride 40), k = mi*16 + lc*4 + 2p
                    *(unsigned int*)&Wt[wtbase + (ni*16 + lr)*40 + mi*16 + lc*4 + 2*p] = packed;
                }
            }
        }
        // ---- PV: A = P[q=lr][k=lc*8..+8] from Wt, B = V frags; acc[ni][nd]
        #pragma unroll
        for (int ni = 0; ni < 4; ++ni) {
            bf16x8 pa = *(const bf16x8*)&Wt[wtbase + (ni*16 + lr)*40 + lc*8];
            #pragma unroll
            for (int nd = 0; nd < 4; ++nd) {
                acc[ni][nd] = __builtin_amdgcn_mfma_f32_16x16x32_bf16(pa, vh[nd], acc[ni][nd], 0, 0, 0);
                acc[ni][nd] = __builtin_amdgcn_mfma_f32_16x16x32_bf16(pa, vl[nd], acc[ni][nd], 0, 0, 0);
            }
        }
    }

    // ---- den: reduce across lc groups (same q, different k subsets)
    #pragma unroll
    for (int ni = 0; ni < 4; ++ni) {
        float d = den[ni];
        d += __shfl_xor(d, 16);
        d += __shfl_xor(d, 32);
        den[ni] = d;
    }
    __syncthreads();   // all Wt reads done; pool now becomes accL
    // ---- write per-wave partials
    {
        float* my = accL + wid * (64*68);
        #pragma unroll
        for (int ni = 0; ni < 4; ++ni)
            #pragma unroll
            for (int nd = 0; nd < 4; ++nd)
                #pragma unroll
                for (int r = 0; r < 4; ++r)
                    my[(ni*16 + lc*4 + r)*68 + nd*16 + lr] = acc[ni][nd][r];
        if (lc == 0) {
            #pragma unroll
            for (int ni = 0; ni < 4; ++ni) denL[wid][ni*16 + lr] = den[ni];
        }
    }
    __syncthreads();
    // ---- sum 4 waves' partials, normalize, store
    {
        const int q  = tid >> 2;            // 0..63
        const int dq = (tid & 3) * 16;      // 0,16,32,48
        float dsum = denL[0][q] + denL[1][q] + denL[2][q] + denL[3][q];
        float mq = masks[b*S_LEN + q0 + q];
        float scale = mq / dsum;
        #pragma unroll
        for (int i = 0; i < 4; ++i) {
            int d = dq + i*4;
            float4 s0 = *(float4*)&accL[0*(64*68) + q*68 + d];
            float4 s1 = *(float4*)&accL[1*(64*68) + q*68 + d];
            float4 s2 = *(float4*)&accL[2*(64*68) + q*68 + d];
            float4 s3 = *(float4*)&accL[3*(64*68) + q*68 + d];
            float4 o = make_float4((s0.x+s1.x+s2.x+s3.x)*scale,
                                   (s0.y+s1.y+s2.y+s3.y)*scale,
                                   (s0.z+s1.z+s2.z+s3.z)*scale,
                                   (s0.w+s1.w+s2.w+s3.w)*scale);
            *(float4*)&out[(srow + q0 + q)*D_MODEL + h*64 + d] = o;
        }
    }
}

extern "C" void kernel_launch(void* const* d_in, const int* in_sizes, int n_in,
                              void* d_out, int out_size, void* d_ws, size_t ws_size,
                              hipStream_t stream) {
    (void)in_sizes; (void)n_in; (void)out_size; (void)ws_size;
    const float* inputs = (const float*)d_in[0];
    const float* masks  = (const float*)d_in[1];
    const float* Wm     = (const float*)d_in[2];
    const float* bias   = (const float*)d_in[3];
    float* outp = (float*)d_out;

    // ws layout (50,331,648 B, same footprint as validated R3/R4):
    unsigned short* khi  = (unsigned short*)d_ws;
    unsigned short* klo  = khi + (size_t)4096*2048;
    unsigned short* vthi = klo + (size_t)4096*2048;
    unsigned short* vtlo = vthi + (size_t)1024*4096;

    gemm_fused<<<dim3(24, 32), 256, 0, stream>>>(inputs, Wm, bias, khi, klo, vthi, vtlo);
    attn_mfma<<<1024, 256, 0, stream>>>(khi, klo, vthi, vtlo, masks, outp);
}